// Round 1
// baseline (508.352 us; speedup 1.0000x reference)
//
#include <hip/hip_runtime.h>

typedef unsigned short u16;
typedef unsigned int u32;
typedef __attribute__((ext_vector_type(8))) short short8;
typedef __attribute__((ext_vector_type(4))) float f32x4;

__device__ __forceinline__ float bf2f(u16 u) {
    return __uint_as_float(((u32)u) << 16);
}
__device__ __forceinline__ u16 f2bf(float f) {
    u32 u = __float_as_uint(f);
    u += 0x7fff + ((u >> 16) & 1);   // round-to-nearest-even
    return (u16)(u >> 16);
}

// ---------------- conversions ----------------

__global__ void cvt_x_kernel(const float* __restrict__ x, u16* __restrict__ xb, int n) {
    int i = blockIdx.x * 256 + threadIdx.x;   // group of 4 elements
    int row = i >> 6;                         // 64 groups per 256-wide row
    ushort4 o;
    if (row < n) {
        float4 v = ((const float4*)x)[i];
        o.x = f2bf(v.x); o.y = f2bf(v.y); o.z = f2bf(v.z); o.w = f2bf(v.w);
    } else {
        o.x = o.y = o.z = o.w = 0;
    }
    ((ushort4*)xb)[i] = o;
}

// wT layout: [layer][n=256][k=512], k-contiguous (transposed weights, A rows then B rows)
__global__ void cvt_w_kernel(const float* __restrict__ WA, const float* __restrict__ WB,
                             const float* __restrict__ As, const float* __restrict__ Bs,
                             u16* __restrict__ wT, int nlayers) {
    int i = blockIdx.x * 256 + threadIdx.x;
    const int per = 256 * 512;
    if (i >= nlayers * per) return;
    int l = i / per;
    int rem = i - l * per;
    int nn = rem >> 9;
    int k = rem & 511;
    const float* Aw = (l == 0) ? WA : As + (size_t)(l - 1) * 65536;
    const float* Bw = (l == 0) ? WB : Bs + (size_t)(l - 1) * 65536;
    float v = (k < 256) ? Aw[(size_t)k * 256 + nn] : Bw[(size_t)(k - 256) * 256 + nn];
    wT[i] = f2bf(v);
}

// ---------------- CSR build ----------------

__global__ void count_kernel(const int* __restrict__ dst, int* __restrict__ deg, int e) {
    int i = blockIdx.x * 256 + threadIdx.x;
    if (i < e) atomicAdd(&deg[dst[i]], 1);
}

__global__ void scan_local_kernel(const int* __restrict__ deg, int* __restrict__ rowptr,
                                  int* __restrict__ bsum, int n) {
    __shared__ int sh[256];
    int t = threadIdx.x;
    int i = blockIdx.x * 256 + t;
    int v = (i < n) ? deg[i] : 0;
    int x = v;
    sh[t] = x; __syncthreads();
    for (int o = 1; o < 256; o <<= 1) {
        int y = (t >= o) ? sh[t - o] : 0;
        __syncthreads();
        x += y; sh[t] = x; __syncthreads();
    }
    if (i < n) rowptr[i] = x - v;       // local exclusive
    if (t == 255) bsum[blockIdx.x] = x; // block total
}

__global__ void scan_block_kernel(const int* __restrict__ bsum, int* __restrict__ boff, int nb) {
    __shared__ int sh[256];
    int t = threadIdx.x;
    int v = (t < nb) ? bsum[t] : 0;
    int x = v;
    sh[t] = x; __syncthreads();
    for (int o = 1; o < 256; o <<= 1) {
        int y = (t >= o) ? sh[t - o] : 0;
        __syncthreads();
        x += y; sh[t] = x; __syncthreads();
    }
    if (t < nb) boff[t] = x - v;
}

__global__ void scan_add_kernel(int* __restrict__ rowptr, const int* __restrict__ boff,
                                const int* __restrict__ deg, float* __restrict__ invd,
                                int n, int e) {
    int i = blockIdx.x * 256 + threadIdx.x;
    if (i < n) {
        rowptr[i] += boff[i >> 8];
        int d = deg[i];
        invd[i] = 1.0f / (float)(d > 0 ? d : 1);
    }
    if (i == 0) rowptr[n] = e;
}

__global__ void fill_kernel(const int* __restrict__ src, const int* __restrict__ dst,
                            const int* __restrict__ rowptr, int* __restrict__ fillc,
                            int* __restrict__ srcs, int e) {
    int i = blockIdx.x * 256 + threadIdx.x;
    if (i >= e) return;
    int d = dst[i];
    int pos = rowptr[d] + atomicAdd(&fillc[d], 1);
    srcs[pos] = src[i];
}

// ---------------- mean aggregation: one wave per node ----------------

__global__ __launch_bounds__(256) void agg_kernel(const u16* __restrict__ cur, u16* __restrict__ mb,
                                                  const int* __restrict__ rowptr,
                                                  const int* __restrict__ srcs,
                                                  const float* __restrict__ invd,
                                                  int n, int npad) {
    int gw = (blockIdx.x * 256 + threadIdx.x) >> 6;  // node id
    int lane = threadIdx.x & 63;                     // lane handles feats [lane*4, lane*4+4)
    if (gw >= npad) return;
    if (gw >= n) {
        ushort4 z; z.x = z.y = z.z = z.w = 0;
        ((ushort4*)(mb + (size_t)gw * 256))[lane] = z;
        return;
    }
    int beg = rowptr[gw], end = rowptr[gw + 1];
    float a0 = 0.f, a1 = 0.f, a2 = 0.f, a3 = 0.f;
    for (int base = beg; base < end; base += 64) {
        int cnt = end - base;
        if (cnt > 64) cnt = 64;
        int sl = (lane < cnt) ? srcs[base + lane] : 0;
        for (int j = 0; j < cnt; ++j) {
            int sj = __shfl(sl, j);
            ushort4 v = ((const ushort4*)(cur + (size_t)sj * 256))[lane];
            a0 += bf2f(v.x); a1 += bf2f(v.y); a2 += bf2f(v.z); a3 += bf2f(v.w);
        }
    }
    float sc = invd[gw];
    ushort4 o;
    o.x = f2bf(a0 * sc); o.y = f2bf(a1 * sc); o.z = f2bf(a2 * sc); o.w = f2bf(a3 * sc);
    ((ushort4*)(mb + (size_t)gw * 256))[lane] = o;
}

// ---------------- fused GEMM: out = act([m | cur] @ wT^T), 128x128 tile ----------------
// A: rows from m (k<256) then cur (k>=256), both [NPAD][256] bf16 row-major.
// B: wT layer slice [n=256][k=512] bf16, k-contiguous.

__global__ __launch_bounds__(256) void gemm_kernel(const u16* __restrict__ mA,
                                                   const u16* __restrict__ cur,
                                                   const u16* __restrict__ wT,
                                                   u16* __restrict__ outb,
                                                   int n, int apply_sigmoid) {
    __shared__ u16 lA[128 * 32];
    __shared__ u16 lB[128 * 32];
    int bid = blockIdx.x;
    int bm = bid >> 1, bn = bid & 1;
    int r0 = bm * 128, c0 = bn * 128;
    int tid = threadIdx.x;
    int lane = tid & 63;
    int w = tid >> 6;
    int wrow = w >> 1, wcol = w & 1;
    int lrow = lane & 15, quad = lane >> 4;

    f32x4 acc[4][4] = {};

    for (int ks = 0; ks < 16; ++ks) {
        int k0 = ks * 32;
        const u16* srcA = (k0 < 256) ? mA : cur;
        int kk = k0 & 255;
        __syncthreads();
#pragma unroll
        for (int p = 0; p < 2; ++p) {
            int li = p * 256 + tid;        // 0..511
            int row = li >> 2;             // 0..127
            int seg = (li & 3) << 3;       // 0,8,16,24
            const u16* gA = srcA + (size_t)(r0 + row) * 256 + kk + seg;
            __builtin_amdgcn_global_load_lds(
                (__attribute__((address_space(1))) u32*)(gA),
                (__attribute__((address_space(3))) u32*)(lA + (size_t)li * 8), 16, 0, 0);
            const u16* gB = wT + (size_t)(c0 + row) * 512 + k0 + seg;
            __builtin_amdgcn_global_load_lds(
                (__attribute__((address_space(1))) u32*)(gB),
                (__attribute__((address_space(3))) u32*)(lB + (size_t)li * 8), 16, 0, 0);
        }
        __syncthreads();

        short8 a[4], b[4];
#pragma unroll
        for (int t = 0; t < 4; ++t) {
            a[t] = *(const short8*)(lA + ((size_t)(wrow * 64 + t * 16 + lrow) * 32 + quad * 8));
            b[t] = *(const short8*)(lB + ((size_t)(wcol * 64 + t * 16 + lrow) * 32 + quad * 8));
        }
#pragma unroll
        for (int rt = 0; rt < 4; ++rt)
#pragma unroll
            for (int ct = 0; ct < 4; ++ct)
                acc[rt][ct] = __builtin_amdgcn_mfma_f32_16x16x32_bf16(a[rt], b[ct], acc[rt][ct], 0, 0, 0);
    }

#pragma unroll
    for (int rt = 0; rt < 4; ++rt) {
        int rbase = r0 + wrow * 64 + rt * 16 + quad * 4;
#pragma unroll
        for (int r = 0; r < 4; ++r) {
            int row = rbase + r;
            if (row < n) {
#pragma unroll
                for (int ct = 0; ct < 4; ++ct) {
                    float v = acc[rt][ct][r];
                    if (apply_sigmoid) v = 1.0f / (1.0f + __expf(-v));
                    outb[(size_t)row * 256 + c0 + wcol * 64 + ct * 16 + lrow] = f2bf(v);
                }
            }
        }
    }
}

// ---------------- final matvec + bias: one wave per node ----------------

__global__ __launch_bounds__(256) void out_kernel(const u16* __restrict__ h,
                                                  const float* __restrict__ wo,
                                                  const float* __restrict__ bo,
                                                  float* __restrict__ out, int n) {
    int gw = (blockIdx.x * 256 + threadIdx.x) >> 6;
    int lane = threadIdx.x & 63;
    if (gw >= n) return;
    ushort4 v = ((const ushort4*)(h + (size_t)gw * 256))[lane];
    float4 wv = ((const float4*)wo)[lane];
    float s = bf2f(v.x) * wv.x + bf2f(v.y) * wv.y + bf2f(v.z) * wv.z + bf2f(v.w) * wv.w;
#pragma unroll
    for (int o = 32; o > 0; o >>= 1) s += __shfl_down(s, o);
    if (lane == 0) out[gw] = s + bo[0];
}

// ---------------- launch ----------------

extern "C" void kernel_launch(void* const* d_in, const int* in_sizes, int n_in,
                              void* d_out, int out_size, void* d_ws, size_t ws_size,
                              hipStream_t stream) {
    const float* x  = (const float*)d_in[0];
    const int*   ei = (const int*)d_in[1];
    const float* WA = (const float*)d_in[2];
    const float* WB = (const float*)d_in[3];
    const float* As = (const float*)d_in[4];
    const float* Bs = (const float*)d_in[5];
    const float* Wo = (const float*)d_in[6];
    const float* bo = (const float*)d_in[7];
    float* out = (float*)d_out;

    const int H = 256;
    int N = in_sizes[0] / H;
    int E = in_sizes[1] / 2;
    int L = in_sizes[4] / (H * H);
    int NPAD = (N + 127) & ~127;
    int nb = (N + 255) / 256;

    char* wsp = (char*)d_ws;
    size_t off = 0;
    auto alloc = [&](size_t b) { size_t o = off; off += (b + 255) & ~(size_t)255; return o; };
    int*   rowptr = (int*)(wsp + alloc((size_t)(NPAD + 1) * 4));
    int*   deg    = (int*)(wsp + alloc((size_t)N * 4));
    int*   fillc  = (int*)(wsp + alloc((size_t)N * 4));
    int*   bsum   = (int*)(wsp + alloc(1024));
    int*   boff   = (int*)(wsp + alloc(1024));
    float* invd   = (float*)(wsp + alloc((size_t)NPAD * 4));
    int*   srcs   = (int*)(wsp + alloc((size_t)E * 4));
    u16*   xb     = (u16*)(wsp + alloc((size_t)NPAD * H * 2));
    u16*   hA     = (u16*)(wsp + alloc((size_t)NPAD * H * 2));
    u16*   hB     = (u16*)(wsp + alloc((size_t)NPAD * H * 2));
    u16*   mb     = (u16*)(wsp + alloc((size_t)NPAD * H * 2));
    u16*   wT     = (u16*)(wsp + alloc((size_t)(L + 1) * 512 * 256 * 2));

    const int* esrc = ei;
    const int* edst = ei + E;

    hipMemsetAsync(deg, 0, (size_t)N * 4, stream);
    hipMemsetAsync(fillc, 0, (size_t)N * 4, stream);

    cvt_x_kernel<<<NPAD / 4, 256, 0, stream>>>(x, xb, N);
    cvt_w_kernel<<<((L + 1) * 512 * 256 + 255) / 256, 256, 0, stream>>>(WA, WB, As, Bs, wT, L + 1);
    count_kernel<<<(E + 255) / 256, 256, 0, stream>>>(edst, deg, E);
    scan_local_kernel<<<nb, 256, 0, stream>>>(deg, rowptr, bsum, N);
    scan_block_kernel<<<1, 256, 0, stream>>>(bsum, boff, nb);
    scan_add_kernel<<<nb, 256, 0, stream>>>(rowptr, boff, deg, invd, N, E);
    fill_kernel<<<(E + 255) / 256, 256, 0, stream>>>(esrc, edst, rowptr, fillc, srcs, E);

    const u16* cur = xb;
    for (int s = 0; s <= L; ++s) {
        u16* nxt = (s & 1) ? hB : hA;
        agg_kernel<<<NPAD / 4, 256, 0, stream>>>(cur, mb, rowptr, srcs, invd, N, NPAD);
        gemm_kernel<<<(NPAD / 128) * 2, 256, 0, stream>>>(mb, cur, wT + (size_t)s * 512 * 256, nxt, N, s > 0 ? 1 : 0);
        cur = nxt;
    }
    out_kernel<<<(N + 3) / 4, 256, 0, stream>>>(cur, Wo, bo, out, N);
}

// Round 2
// 440.841 us; speedup vs baseline: 1.1531x; 1.1531x over previous
//
#include <hip/hip_runtime.h>

typedef unsigned short u16;
typedef unsigned int u32;
typedef __attribute__((ext_vector_type(8))) short short8;
typedef __attribute__((ext_vector_type(4))) float f32x4;

__device__ __forceinline__ float bf2f(u16 u) {
    return __uint_as_float(((u32)u) << 16);
}
__device__ __forceinline__ u16 f2bf(float f) {
    u32 u = __float_as_uint(f);
    u += 0x7fff + ((u >> 16) & 1);   // round-to-nearest-even
    return (u16)(u >> 16);
}
__device__ __forceinline__ u32 pack2(float a, float b) {
    return (u32)f2bf(a) | ((u32)f2bf(b) << 16);
}

// ---------------- conversions ----------------

__global__ void cvt_x_kernel(const float* __restrict__ x, u16* __restrict__ xb, int n) {
    int i = blockIdx.x * 256 + threadIdx.x;   // group of 4 elements
    int row = i >> 6;                         // 64 groups per 256-wide row
    ushort4 o;
    if (row < n) {
        float4 v = ((const float4*)x)[i];
        o.x = f2bf(v.x); o.y = f2bf(v.y); o.z = f2bf(v.z); o.w = f2bf(v.w);
    } else {
        o.x = o.y = o.z = o.w = 0;
    }
    ((ushort4*)xb)[i] = o;
}

// wT layout: [layer][n=256][k=512], k-contiguous (transposed weights, A rows then B rows)
__global__ void cvt_w_kernel(const float* __restrict__ WA, const float* __restrict__ WB,
                             const float* __restrict__ As, const float* __restrict__ Bs,
                             u16* __restrict__ wT, int nlayers) {
    int i = blockIdx.x * 256 + threadIdx.x;
    const int per = 256 * 512;
    if (i >= nlayers * per) return;
    int l = i / per;
    int rem = i - l * per;
    int nn = rem >> 9;
    int k = rem & 511;
    const float* Aw = (l == 0) ? WA : As + (size_t)(l - 1) * 65536;
    const float* Bw = (l == 0) ? WB : Bs + (size_t)(l - 1) * 65536;
    float v = (k < 256) ? Aw[(size_t)k * 256 + nn] : Bw[(size_t)(k - 256) * 256 + nn];
    wT[i] = f2bf(v);
}

// ---------------- CSR build ----------------

__global__ void count_kernel(const int* __restrict__ dst, int* __restrict__ deg, int e) {
    int i = blockIdx.x * 256 + threadIdx.x;
    if (i < e) atomicAdd(&deg[dst[i]], 1);
}

__global__ void scan_local_kernel(const int* __restrict__ deg, int* __restrict__ rowptr,
                                  int* __restrict__ bsum, int n) {
    __shared__ int sh[256];
    int t = threadIdx.x;
    int i = blockIdx.x * 256 + t;
    int v = (i < n) ? deg[i] : 0;
    int x = v;
    sh[t] = x; __syncthreads();
    for (int o = 1; o < 256; o <<= 1) {
        int y = (t >= o) ? sh[t - o] : 0;
        __syncthreads();
        x += y; sh[t] = x; __syncthreads();
    }
    if (i < n) rowptr[i] = x - v;       // local exclusive
    if (t == 255) bsum[blockIdx.x] = x; // block total
}

__global__ void scan_block_kernel(const int* __restrict__ bsum, int* __restrict__ boff, int nb) {
    __shared__ int sh[256];
    int t = threadIdx.x;
    int v = (t < nb) ? bsum[t] : 0;
    int x = v;
    sh[t] = x; __syncthreads();
    for (int o = 1; o < 256; o <<= 1) {
        int y = (t >= o) ? sh[t - o] : 0;
        __syncthreads();
        x += y; sh[t] = x; __syncthreads();
    }
    if (t < nb) boff[t] = x - v;
}

__global__ void scan_add_kernel(int* __restrict__ rowptr, const int* __restrict__ boff,
                                const int* __restrict__ deg, float* __restrict__ invd,
                                int n, int e) {
    int i = blockIdx.x * 256 + threadIdx.x;
    if (i < n) {
        rowptr[i] += boff[i >> 8];
        int d = deg[i];
        invd[i] = 1.0f / (float)(d > 0 ? d : 1);
    }
    if (i == 0) rowptr[n] = e;
}

__global__ void fill_kernel(const int* __restrict__ src, const int* __restrict__ dst,
                            const int* __restrict__ rowptr, int* __restrict__ fillc,
                            int* __restrict__ srcs, int e) {
    int i = blockIdx.x * 256 + threadIdx.x;
    if (i >= e) return;
    int d = dst[i];
    int pos = rowptr[d] + atomicAdd(&fillc[d], 1);
    srcs[pos] = src[i];
}

// ---------------- mean aggregation: one wave per node ----------------
// 32 lanes cover one 512B row (16B/lane); halves of the wave take alternating
// edges; unrolled x2 -> 4 edges in flight per iteration.

__global__ __launch_bounds__(256) void agg_kernel(const u16* __restrict__ cur, u16* __restrict__ mb,
                                                  const int* __restrict__ rowptr,
                                                  const int* __restrict__ srcs,
                                                  const float* __restrict__ invd,
                                                  int n, int npad) {
    int gw = (blockIdx.x * 256 + threadIdx.x) >> 6;  // node id
    int lane = threadIdx.x & 63;
    int half = lane >> 5;        // which edge of a pair
    int fl = lane & 31;          // 16B feature group within the row
    if (gw >= npad) return;
    u16* orow = mb + (size_t)gw * 256;
    if (gw >= n) {
        if (half == 0) {
            uint4 z; z.x = z.y = z.z = z.w = 0;
            ((uint4*)orow)[fl] = z;
        }
        return;
    }
    int beg = rowptr[gw], end = rowptr[gw + 1];
    float a0 = 0.f, a1 = 0.f, a2 = 0.f, a3 = 0.f,
          a4 = 0.f, a5 = 0.f, a6 = 0.f, a7 = 0.f;
    for (int base = beg; base < end; base += 64) {
        int cnt = end - base;
        if (cnt > 64) cnt = 64;
        int el = (lane < cnt) ? srcs[base + lane] : 0;
        int t = 0;
        // main: 4 fully-valid edges per iteration
        for (; 2 * t + 4 <= cnt; t += 2) {
            int e0 = 2 * t + half;
            int e1 = e0 + 2;
            int s0 = __shfl(el, e0);
            int s1 = __shfl(el, e1);
            uint4 v0 = *(const uint4*)(cur + (size_t)s0 * 256 + fl * 8);
            uint4 v1 = *(const uint4*)(cur + (size_t)s1 * 256 + fl * 8);
            a0 += __uint_as_float(v0.x << 16); a1 += __uint_as_float(v0.x & 0xffff0000u);
            a2 += __uint_as_float(v0.y << 16); a3 += __uint_as_float(v0.y & 0xffff0000u);
            a4 += __uint_as_float(v0.z << 16); a5 += __uint_as_float(v0.z & 0xffff0000u);
            a6 += __uint_as_float(v0.w << 16); a7 += __uint_as_float(v0.w & 0xffff0000u);
            a0 += __uint_as_float(v1.x << 16); a1 += __uint_as_float(v1.x & 0xffff0000u);
            a2 += __uint_as_float(v1.y << 16); a3 += __uint_as_float(v1.y & 0xffff0000u);
            a4 += __uint_as_float(v1.z << 16); a5 += __uint_as_float(v1.z & 0xffff0000u);
            a6 += __uint_as_float(v1.w << 16); a7 += __uint_as_float(v1.w & 0xffff0000u);
        }
        // tail: masked
        for (; 2 * t < cnt; ++t) {
            int ei = 2 * t + half;
            int sj = __shfl(el, ei & 63);
            float m = (ei < cnt) ? 1.0f : 0.0f;
            uint4 v = *(const uint4*)(cur + (size_t)sj * 256 + fl * 8);
            a0 += m * __uint_as_float(v.x << 16); a1 += m * __uint_as_float(v.x & 0xffff0000u);
            a2 += m * __uint_as_float(v.y << 16); a3 += m * __uint_as_float(v.y & 0xffff0000u);
            a4 += m * __uint_as_float(v.z << 16); a5 += m * __uint_as_float(v.z & 0xffff0000u);
            a6 += m * __uint_as_float(v.w << 16); a7 += m * __uint_as_float(v.w & 0xffff0000u);
        }
    }
    // combine the two halves
    a0 += __shfl_down(a0, 32); a1 += __shfl_down(a1, 32);
    a2 += __shfl_down(a2, 32); a3 += __shfl_down(a3, 32);
    a4 += __shfl_down(a4, 32); a5 += __shfl_down(a5, 32);
    a6 += __shfl_down(a6, 32); a7 += __shfl_down(a7, 32);
    if (half == 0) {
        float sc = invd[gw];
        uint4 o;
        o.x = pack2(a0 * sc, a1 * sc);
        o.y = pack2(a2 * sc, a3 * sc);
        o.z = pack2(a4 * sc, a5 * sc);
        o.w = pack2(a6 * sc, a7 * sc);
        ((uint4*)orow)[fl] = o;
    }
}

// ---------------- fused GEMM: out = act([m | cur] @ wT^T), 128x256 tile ----------------
// A: rows from m (k<256) then cur (k>=256), both [NPAD][256] bf16 row-major.
// B: wT layer slice [n=256][k=512] bf16, k-contiguous. One block covers all 256 cols.
// fin=1: instead of storing h, dot rows against wo (fp32 [256]) + bias -> out[row].

__global__ __launch_bounds__(256, 2) void gemm_kernel(const u16* __restrict__ mA,
                                                      const u16* __restrict__ cur,
                                                      const u16* __restrict__ wT,
                                                      u16* __restrict__ outb,
                                                      const float* __restrict__ wo,
                                                      const float* __restrict__ bo,
                                                      float* __restrict__ out,
                                                      int n, int apply_sigmoid, int fin) {
    __shared__ u16 lA[128 * 32];
    __shared__ u16 lB[256 * 32];
    __shared__ float lO[2][128];
    int r0 = blockIdx.x * 128;
    int tid = threadIdx.x;
    int lane = tid & 63;
    int w = tid >> 6;
    int wrow = w >> 1, wcol = w & 1;   // wave: rows wrow*64.., cols wcol*128..
    int lrow = lane & 15, quad = lane >> 4;

    f32x4 acc[4][8] = {};

    for (int ks = 0; ks < 16; ++ks) {
        int k0 = ks * 32;
        const u16* srcA = (k0 < 256) ? mA : cur;
        int kk = k0 & 255;
        __syncthreads();
#pragma unroll
        for (int p = 0; p < 2; ++p) {
            int li = p * 256 + tid;        // 0..511
            int row = li >> 2;             // 0..127
            int seg = (li & 3) << 3;       // elem offset 0,8,16,24
            const u16* gA = srcA + (size_t)(r0 + row) * 256 + kk + seg;
            __builtin_amdgcn_global_load_lds(
                (__attribute__((address_space(1))) u32*)(gA),
                (__attribute__((address_space(3))) u32*)(lA + (size_t)li * 8), 16, 0, 0);
        }
#pragma unroll
        for (int p = 0; p < 4; ++p) {
            int li = p * 256 + tid;        // 0..1023
            int row = li >> 2;             // 0..255
            int seg = (li & 3) << 3;
            const u16* gB = wT + (size_t)row * 512 + k0 + seg;
            __builtin_amdgcn_global_load_lds(
                (__attribute__((address_space(1))) u32*)(gB),
                (__attribute__((address_space(3))) u32*)(lB + (size_t)li * 8), 16, 0, 0);
        }
        __syncthreads();

        short8 a[4], b[8];
#pragma unroll
        for (int t = 0; t < 4; ++t)
            a[t] = *(const short8*)(lA + ((size_t)(wrow * 64 + t * 16 + lrow) * 32 + quad * 8));
#pragma unroll
        for (int t = 0; t < 8; ++t)
            b[t] = *(const short8*)(lB + ((size_t)(wcol * 128 + t * 16 + lrow) * 32 + quad * 8));
#pragma unroll
        for (int rt = 0; rt < 4; ++rt)
#pragma unroll
            for (int ct = 0; ct < 8; ++ct)
                acc[rt][ct] = __builtin_amdgcn_mfma_f32_16x16x32_bf16(a[rt], b[ct], acc[rt][ct], 0, 0, 0);
    }

    if (!fin) {
#pragma unroll
        for (int rt = 0; rt < 4; ++rt) {
            int rbase = r0 + wrow * 64 + rt * 16 + quad * 4;
#pragma unroll
            for (int r = 0; r < 4; ++r) {
                int row = rbase + r;
                if (row < n) {
#pragma unroll
                    for (int ct = 0; ct < 8; ++ct) {
                        float v = acc[rt][ct][r];
                        if (apply_sigmoid) v = 1.0f / (1.0f + __expf(-v));
                        outb[(size_t)row * 256 + wcol * 128 + ct * 16 + lrow] = f2bf(v);
                    }
                }
            }
        }
    } else {
        // final layer: sigmoid then dot with wo, reduce, write out
        float wv[8];
#pragma unroll
        for (int ct = 0; ct < 8; ++ct) wv[ct] = wo[wcol * 128 + ct * 16 + lrow];
#pragma unroll
        for (int rt = 0; rt < 4; ++rt) {
#pragma unroll
            for (int r = 0; r < 4; ++r) {
                float s = 0.f;
#pragma unroll
                for (int ct = 0; ct < 8; ++ct) {
                    float v = acc[rt][ct][r];
                    v = 1.0f / (1.0f + __expf(-v));
                    s += v * wv[ct];
                }
                // reduce across the 16 lanes (lrow bits 0..3) sharing this row
                s += __shfl_xor(s, 1);
                s += __shfl_xor(s, 2);
                s += __shfl_xor(s, 4);
                s += __shfl_xor(s, 8);
                if (lrow == 0) {
                    int rowlocal = wrow * 64 + rt * 16 + quad * 4 + r;
                    lO[wcol][rowlocal] = s;
                }
            }
        }
        __syncthreads();
        if (tid < 128) {
            int row = r0 + tid;
            if (row < n) out[row] = lO[0][tid] + lO[1][tid] + bo[0];
        }
    }
}

// ---------------- launch ----------------

extern "C" void kernel_launch(void* const* d_in, const int* in_sizes, int n_in,
                              void* d_out, int out_size, void* d_ws, size_t ws_size,
                              hipStream_t stream) {
    const float* x  = (const float*)d_in[0];
    const int*   ei = (const int*)d_in[1];
    const float* WA = (const float*)d_in[2];
    const float* WB = (const float*)d_in[3];
    const float* As = (const float*)d_in[4];
    const float* Bs = (const float*)d_in[5];
    const float* Wo = (const float*)d_in[6];
    const float* bo = (const float*)d_in[7];
    float* out = (float*)d_out;

    const int H = 256;
    int N = in_sizes[0] / H;
    int E = in_sizes[1] / 2;
    int L = in_sizes[4] / (H * H);
    int NPAD = (N + 127) & ~127;
    int nb = (N + 255) / 256;

    char* wsp = (char*)d_ws;
    size_t off = 0;
    auto alloc = [&](size_t b) { size_t o = off; off += (b + 255) & ~(size_t)255; return o; };
    int*   rowptr = (int*)(wsp + alloc((size_t)(NPAD + 1) * 4));
    int*   deg    = (int*)(wsp + alloc((size_t)N * 4));
    int*   fillc  = (int*)(wsp + alloc((size_t)N * 4));
    int*   bsum   = (int*)(wsp + alloc(1024));
    int*   boff   = (int*)(wsp + alloc(1024));
    float* invd   = (float*)(wsp + alloc((size_t)NPAD * 4));
    int*   srcs   = (int*)(wsp + alloc((size_t)E * 4));
    u16*   xb     = (u16*)(wsp + alloc((size_t)NPAD * H * 2));
    u16*   hA     = (u16*)(wsp + alloc((size_t)NPAD * H * 2));
    u16*   hB     = (u16*)(wsp + alloc((size_t)NPAD * H * 2));
    u16*   mb     = (u16*)(wsp + alloc((size_t)NPAD * H * 2));
    u16*   wT     = (u16*)(wsp + alloc((size_t)(L + 1) * 512 * 256 * 2));

    const int* esrc = ei;
    const int* edst = ei + E;

    hipMemsetAsync(deg, 0, (size_t)N * 4, stream);
    hipMemsetAsync(fillc, 0, (size_t)N * 4, stream);

    cvt_x_kernel<<<NPAD / 4, 256, 0, stream>>>(x, xb, N);
    cvt_w_kernel<<<((L + 1) * 512 * 256 + 255) / 256, 256, 0, stream>>>(WA, WB, As, Bs, wT, L + 1);
    count_kernel<<<(E + 255) / 256, 256, 0, stream>>>(edst, deg, E);
    scan_local_kernel<<<nb, 256, 0, stream>>>(deg, rowptr, bsum, N);
    scan_block_kernel<<<1, 256, 0, stream>>>(bsum, boff, nb);
    scan_add_kernel<<<nb, 256, 0, stream>>>(rowptr, boff, deg, invd, N, E);
    fill_kernel<<<(E + 255) / 256, 256, 0, stream>>>(esrc, edst, rowptr, fillc, srcs, E);

    const u16* cur = xb;
    for (int s = 0; s <= L; ++s) {
        u16* nxt = (s & 1) ? hB : hA;
        int fin = (s == L) ? 1 : 0;
        agg_kernel<<<NPAD / 4, 256, 0, stream>>>(cur, mb, rowptr, srcs, invd, N, NPAD);
        gemm_kernel<<<NPAD / 128, 256, 0, stream>>>(mb, cur, wT + (size_t)s * 512 * 256, nxt,
                                                    Wo, bo, out, N, s > 0 ? 1 : 0, fin);
        cur = nxt;
    }
}

// Round 3
// 392.408 us; speedup vs baseline: 1.2955x; 1.1234x over previous
//
#include <hip/hip_runtime.h>

typedef unsigned short u16;
typedef unsigned int u32;
typedef __attribute__((ext_vector_type(8))) short short8;
typedef __attribute__((ext_vector_type(4))) float f32x4;
typedef __attribute__((ext_vector_type(2))) float f32x2;

__device__ __forceinline__ float bf2f(u16 u) {
    return __uint_as_float(((u32)u) << 16);
}
__device__ __forceinline__ u16 f2bf(float f) {
    u32 u = __float_as_uint(f);
    u += 0x7fff + ((u >> 16) & 1);   // round-to-nearest-even
    return (u16)(u >> 16);
}
__device__ __forceinline__ u32 pack2(float a, float b) {
    return (u32)f2bf(a) | ((u32)f2bf(b) << 16);
}
// pack 4 floats -> 4 fp8 e4m3 in one u32
__device__ __forceinline__ u32 pk_fp8x4(float f0, float f1, float f2, float f3) {
    int w = __builtin_amdgcn_cvt_pk_fp8_f32(f0, f1, 0, false);
    w = __builtin_amdgcn_cvt_pk_fp8_f32(f2, f3, w, true);
    return (u32)w;
}
// accumulate 4 fp8 (one u32) into a[0..3]
__device__ __forceinline__ void acc4(float* a, u32 w) {
    f32x2 lo = __builtin_amdgcn_cvt_pk_f32_fp8((int)w, false);
    f32x2 hi = __builtin_amdgcn_cvt_pk_f32_fp8((int)w, true);
    a[0] += lo.x; a[1] += lo.y; a[2] += hi.x; a[3] += hi.y;
}
__device__ __forceinline__ void acc4m(float* a, u32 w, float m) {
    f32x2 lo = __builtin_amdgcn_cvt_pk_f32_fp8((int)w, false);
    f32x2 hi = __builtin_amdgcn_cvt_pk_f32_fp8((int)w, true);
    a[0] += m * lo.x; a[1] += m * lo.y; a[2] += m * hi.x; a[3] += m * hi.y;
}
__device__ __forceinline__ void acc16(float* a, uint4 v) {
    acc4(a + 0, v.x); acc4(a + 4, v.y); acc4(a + 8, v.z); acc4(a + 12, v.w);
}
__device__ __forceinline__ void acc16m(float* a, uint4 v, float m) {
    acc4m(a + 0, v.x, m); acc4m(a + 4, v.y, m); acc4m(a + 8, v.z, m); acc4m(a + 12, v.w, m);
}

// ---------------- conversions ----------------

// x fp32 -> xb bf16 [NPAD][256]  and  xq fp8 [NPAD][256]
__global__ void cvt_x_kernel(const float* __restrict__ x, u16* __restrict__ xb,
                             u32* __restrict__ xq, int n) {
    int i = blockIdx.x * 256 + threadIdx.x;   // group of 4 elements
    int row = i >> 6;                         // 64 groups per 256-wide row
    ushort4 o;
    u32 q;
    if (row < n) {
        float4 v = ((const float4*)x)[i];
        o.x = f2bf(v.x); o.y = f2bf(v.y); o.z = f2bf(v.z); o.w = f2bf(v.w);
        q = pk_fp8x4(v.x, v.y, v.z, v.w);
    } else {
        o.x = o.y = o.z = o.w = 0;
        q = 0;
    }
    ((ushort4*)xb)[i] = o;
    xq[i] = q;
}

// h bf16 -> fp8 copy (8 feats per thread)
__global__ void cvt_h_kernel(const u16* __restrict__ hb, uint2* __restrict__ hq, int ngroups) {
    int j = blockIdx.x * 256 + threadIdx.x;
    if (j >= ngroups) return;
    uint4 v = ((const uint4*)hb)[j];
    float f0 = bf2f(v.x & 0xffff), f1 = bf2f(v.x >> 16);
    float f2 = bf2f(v.y & 0xffff), f3 = bf2f(v.y >> 16);
    float f4 = bf2f(v.z & 0xffff), f5 = bf2f(v.z >> 16);
    float f6 = bf2f(v.w & 0xffff), f7 = bf2f(v.w >> 16);
    uint2 o;
    o.x = pk_fp8x4(f0, f1, f2, f3);
    o.y = pk_fp8x4(f4, f5, f6, f7);
    hq[j] = o;
}

// wT layout: [layer][n=256][k=512], k-contiguous (transposed weights, A rows then B rows)
__global__ void cvt_w_kernel(const float* __restrict__ WA, const float* __restrict__ WB,
                             const float* __restrict__ As, const float* __restrict__ Bs,
                             u16* __restrict__ wT, int nlayers) {
    int i = blockIdx.x * 256 + threadIdx.x;
    const int per = 256 * 512;
    if (i >= nlayers * per) return;
    int l = i / per;
    int rem = i - l * per;
    int nn = rem >> 9;
    int k = rem & 511;
    const float* Aw = (l == 0) ? WA : As + (size_t)(l - 1) * 65536;
    const float* Bw = (l == 0) ? WB : Bs + (size_t)(l - 1) * 65536;
    float v = (k < 256) ? Aw[(size_t)k * 256 + nn] : Bw[(size_t)(k - 256) * 256 + nn];
    wT[i] = f2bf(v);
}

// ---------------- CSR build ----------------

__global__ void count_kernel(const int* __restrict__ dst, int* __restrict__ deg, int e) {
    int i = blockIdx.x * 256 + threadIdx.x;
    if (i < e) atomicAdd(&deg[dst[i]], 1);
}

__global__ void scan_local_kernel(const int* __restrict__ deg, int* __restrict__ rowptr,
                                  int* __restrict__ bsum, int n) {
    __shared__ int sh[256];
    int t = threadIdx.x;
    int i = blockIdx.x * 256 + t;
    int v = (i < n) ? deg[i] : 0;
    int x = v;
    sh[t] = x; __syncthreads();
    for (int o = 1; o < 256; o <<= 1) {
        int y = (t >= o) ? sh[t - o] : 0;
        __syncthreads();
        x += y; sh[t] = x; __syncthreads();
    }
    if (i < n) rowptr[i] = x - v;       // local exclusive
    if (t == 255) bsum[blockIdx.x] = x; // block total
}

__global__ void scan_block_kernel(const int* __restrict__ bsum, int* __restrict__ boff, int nb) {
    __shared__ int sh[256];
    int t = threadIdx.x;
    int v = (t < nb) ? bsum[t] : 0;
    int x = v;
    sh[t] = x; __syncthreads();
    for (int o = 1; o < 256; o <<= 1) {
        int y = (t >= o) ? sh[t - o] : 0;
        __syncthreads();
        x += y; sh[t] = x; __syncthreads();
    }
    if (t < nb) boff[t] = x - v;
}

__global__ void scan_add_kernel(int* __restrict__ rowptr, const int* __restrict__ boff,
                                const int* __restrict__ deg, float* __restrict__ invd,
                                int n, int e) {
    int i = blockIdx.x * 256 + threadIdx.x;
    if (i < n) {
        rowptr[i] += boff[i >> 8];
        int d = deg[i];
        invd[i] = 1.0f / (float)(d > 0 ? d : 1);
    }
    if (i == 0) rowptr[n] = e;
}

__global__ void fill_kernel(const int* __restrict__ src, const int* __restrict__ dst,
                            const int* __restrict__ rowptr, int* __restrict__ fillc,
                            int* __restrict__ srcs, int e) {
    int i = blockIdx.x * 256 + threadIdx.x;
    if (i >= e) return;
    int d = dst[i];
    int pos = rowptr[d] + atomicAdd(&fillc[d], 1);
    srcs[pos] = src[i];
}

// ---------------- mean aggregation: one wave per node, fp8 gather ----------------
// fp8 row = 256B; 16 lanes x 16B cover a row; 4 edges per wave-load, x2 unroll
// -> 8 edges in flight. Output mean row written as bf16 to mb.

__global__ __launch_bounds__(256) void agg_kernel(const unsigned char* __restrict__ q,
                                                  u16* __restrict__ mb,
                                                  const int* __restrict__ rowptr,
                                                  const int* __restrict__ srcs,
                                                  const float* __restrict__ invd,
                                                  int n, int npad) {
    int gw = (blockIdx.x * 256 + threadIdx.x) >> 6;  // node id
    int lane = threadIdx.x & 63;
    int qd = lane >> 4;          // edge slot within group of 4
    int fl = lane & 15;          // 16B chunk (16 feats) within the row
    if (gw >= npad) return;
    u16* orow = mb + (size_t)gw * 256;
    if (gw >= n) {
        if (lane < 16) {
            uint4 z; z.x = z.y = z.z = z.w = 0;
            uint4* p = (uint4*)(orow + lane * 16);
            p[0] = z; p[1] = z;
        }
        return;
    }
    int beg = rowptr[gw], end = rowptr[gw + 1];
    float a[16];
#pragma unroll
    for (int i = 0; i < 16; ++i) a[i] = 0.f;
    for (int base = beg; base < end; base += 64) {
        int cnt = end - base;
        if (cnt > 64) cnt = 64;
        int el = (lane < cnt) ? srcs[base + lane] : 0;
        int t = 0;
        for (; 4 * t + 8 <= cnt; t += 2) {
            int s0 = __shfl(el, 4 * t + qd);
            int s1 = __shfl(el, 4 * t + 4 + qd);
            uint4 v0 = *(const uint4*)(q + (size_t)s0 * 256 + fl * 16);
            uint4 v1 = *(const uint4*)(q + (size_t)s1 * 256 + fl * 16);
            acc16(a, v0);
            acc16(a, v1);
        }
        for (; 4 * t < cnt; ++t) {
            int ei = 4 * t + qd;
            int sj = __shfl(el, ei & 63);
            float m = (ei < cnt) ? 1.0f : 0.0f;
            uint4 v = *(const uint4*)(q + (size_t)sj * 256 + fl * 16);
            acc16m(a, v, m);
        }
    }
    // reduce the 4 quarters
#pragma unroll
    for (int i = 0; i < 16; ++i) {
        a[i] += __shfl_xor(a[i], 16);
        a[i] += __shfl_xor(a[i], 32);
    }
    if (lane < 16) {
        float sc = invd[gw];
        uint4 o0, o1;
        o0.x = pack2(a[0] * sc, a[1] * sc);
        o0.y = pack2(a[2] * sc, a[3] * sc);
        o0.z = pack2(a[4] * sc, a[5] * sc);
        o0.w = pack2(a[6] * sc, a[7] * sc);
        o1.x = pack2(a[8] * sc, a[9] * sc);
        o1.y = pack2(a[10] * sc, a[11] * sc);
        o1.z = pack2(a[12] * sc, a[13] * sc);
        o1.w = pack2(a[14] * sc, a[15] * sc);
        uint4* p = (uint4*)(orow + lane * 16);
        p[0] = o0; p[1] = o1;
    }
}

// ---------------- fused GEMM: out = act([m | cur] @ wT^T), 128x256 tile ----------------
// A: rows from m (k<256) then cur (k>=256), both [NPAD][256] bf16 row-major.
// B: wT layer slice [n=256][k=512] bf16, k-contiguous. One block covers all 256 cols.
// fin=1: instead of storing h, dot rows against wo (fp32 [256]) + bias -> out[row].

__global__ __launch_bounds__(256, 2) void gemm_kernel(const u16* __restrict__ mA,
                                                      const u16* __restrict__ cur,
                                                      const u16* __restrict__ wT,
                                                      u16* __restrict__ outb,
                                                      const float* __restrict__ wo,
                                                      const float* __restrict__ bo,
                                                      float* __restrict__ out,
                                                      int n, int apply_sigmoid, int fin) {
    __shared__ u16 lA[128 * 32];
    __shared__ u16 lB[256 * 32];
    __shared__ float lO[2][128];
    int r0 = blockIdx.x * 128;
    int tid = threadIdx.x;
    int lane = tid & 63;
    int w = tid >> 6;
    int wrow = w >> 1, wcol = w & 1;   // wave: rows wrow*64.., cols wcol*128..
    int lrow = lane & 15, quad = lane >> 4;

    f32x4 acc[4][8] = {};

    for (int ks = 0; ks < 16; ++ks) {
        int k0 = ks * 32;
        const u16* srcA = (k0 < 256) ? mA : cur;
        int kk = k0 & 255;
        __syncthreads();
#pragma unroll
        for (int p = 0; p < 2; ++p) {
            int li = p * 256 + tid;        // 0..511
            int row = li >> 2;             // 0..127
            int seg = (li & 3) << 3;       // elem offset 0,8,16,24
            const u16* gA = srcA + (size_t)(r0 + row) * 256 + kk + seg;
            __builtin_amdgcn_global_load_lds(
                (__attribute__((address_space(1))) u32*)(gA),
                (__attribute__((address_space(3))) u32*)(lA + (size_t)li * 8), 16, 0, 0);
        }
#pragma unroll
        for (int p = 0; p < 4; ++p) {
            int li = p * 256 + tid;        // 0..1023
            int row = li >> 2;             // 0..255
            int seg = (li & 3) << 3;
            const u16* gB = wT + (size_t)row * 512 + k0 + seg;
            __builtin_amdgcn_global_load_lds(
                (__attribute__((address_space(1))) u32*)(gB),
                (__attribute__((address_space(3))) u32*)(lB + (size_t)li * 8), 16, 0, 0);
        }
        __syncthreads();

        short8 a[4], b[8];
#pragma unroll
        for (int t = 0; t < 4; ++t)
            a[t] = *(const short8*)(lA + ((size_t)(wrow * 64 + t * 16 + lrow) * 32 + quad * 8));
#pragma unroll
        for (int t = 0; t < 8; ++t)
            b[t] = *(const short8*)(lB + ((size_t)(wcol * 128 + t * 16 + lrow) * 32 + quad * 8));
#pragma unroll
        for (int rt = 0; rt < 4; ++rt)
#pragma unroll
            for (int ct = 0; ct < 8; ++ct)
                acc[rt][ct] = __builtin_amdgcn_mfma_f32_16x16x32_bf16(a[rt], b[ct], acc[rt][ct], 0, 0, 0);
    }

    if (!fin) {
#pragma unroll
        for (int rt = 0; rt < 4; ++rt) {
            int rbase = r0 + wrow * 64 + rt * 16 + quad * 4;
#pragma unroll
            for (int r = 0; r < 4; ++r) {
                int row = rbase + r;
                if (row < n) {
#pragma unroll
                    for (int ct = 0; ct < 8; ++ct) {
                        float v = acc[rt][ct][r];
                        if (apply_sigmoid) v = 1.0f / (1.0f + __expf(-v));
                        outb[(size_t)row * 256 + wcol * 128 + ct * 16 + lrow] = f2bf(v);
                    }
                }
            }
        }
    } else {
        // final layer: sigmoid then dot with wo, reduce, write out
        float wv[8];
#pragma unroll
        for (int ct = 0; ct < 8; ++ct) wv[ct] = wo[wcol * 128 + ct * 16 + lrow];
#pragma unroll
        for (int rt = 0; rt < 4; ++rt) {
#pragma unroll
            for (int r = 0; r < 4; ++r) {
                float s = 0.f;
#pragma unroll
                for (int ct = 0; ct < 8; ++ct) {
                    float v = acc[rt][ct][r];
                    v = 1.0f / (1.0f + __expf(-v));
                    s += v * wv[ct];
                }
                // reduce across the 16 lanes (lrow bits 0..3) sharing this row
                s += __shfl_xor(s, 1);
                s += __shfl_xor(s, 2);
                s += __shfl_xor(s, 4);
                s += __shfl_xor(s, 8);
                if (lrow == 0) {
                    int rowlocal = wrow * 64 + rt * 16 + quad * 4 + r;
                    lO[wcol][rowlocal] = s;
                }
            }
        }
        __syncthreads();
        if (tid < 128) {
            int row = r0 + tid;
            if (row < n) out[row] = lO[0][tid] + lO[1][tid] + bo[0];
        }
    }
}

// ---------------- launch ----------------

extern "C" void kernel_launch(void* const* d_in, const int* in_sizes, int n_in,
                              void* d_out, int out_size, void* d_ws, size_t ws_size,
                              hipStream_t stream) {
    const float* x  = (const float*)d_in[0];
    const int*   ei = (const int*)d_in[1];
    const float* WA = (const float*)d_in[2];
    const float* WB = (const float*)d_in[3];
    const float* As = (const float*)d_in[4];
    const float* Bs = (const float*)d_in[5];
    const float* Wo = (const float*)d_in[6];
    const float* bo = (const float*)d_in[7];
    float* out = (float*)d_out;

    const int H = 256;
    int N = in_sizes[0] / H;
    int E = in_sizes[1] / 2;
    int L = in_sizes[4] / (H * H);
    int NPAD = (N + 127) & ~127;
    int nb = (N + 255) / 256;

    char* wsp = (char*)d_ws;
    size_t off = 0;
    auto alloc = [&](size_t b) { size_t o = off; off += (b + 255) & ~(size_t)255; return o; };
    int*   rowptr = (int*)(wsp + alloc((size_t)(NPAD + 1) * 4));
    int*   deg    = (int*)(wsp + alloc((size_t)N * 4));
    int*   fillc  = (int*)(wsp + alloc((size_t)N * 4));
    int*   bsum   = (int*)(wsp + alloc(1024));
    int*   boff   = (int*)(wsp + alloc(1024));
    float* invd   = (float*)(wsp + alloc((size_t)NPAD * 4));
    int*   srcs   = (int*)(wsp + alloc((size_t)E * 4));
    u16*   xb     = (u16*)(wsp + alloc((size_t)NPAD * H * 2));
    u16*   hbuf   = (u16*)(wsp + alloc((size_t)NPAD * H * 2));
    u16*   mb     = (u16*)(wsp + alloc((size_t)NPAD * H * 2));
    u32*   xq     = (u32*)(wsp + alloc((size_t)NPAD * H));      // fp8 x
    uint2* hq     = (uint2*)(wsp + alloc((size_t)NPAD * H));    // fp8 h
    u16*   wT     = (u16*)(wsp + alloc((size_t)(L + 1) * 512 * 256 * 2));

    const int* esrc = ei;
    const int* edst = ei + E;

    hipMemsetAsync(deg, 0, (size_t)N * 4, stream);
    hipMemsetAsync(fillc, 0, (size_t)N * 4, stream);

    cvt_x_kernel<<<NPAD / 4, 256, 0, stream>>>(x, xb, xq, N);
    cvt_w_kernel<<<((L + 1) * 512 * 256 + 255) / 256, 256, 0, stream>>>(WA, WB, As, Bs, wT, L + 1);
    count_kernel<<<(E + 255) / 256, 256, 0, stream>>>(edst, deg, E);
    scan_local_kernel<<<nb, 256, 0, stream>>>(deg, rowptr, bsum, N);
    scan_block_kernel<<<1, 256, 0, stream>>>(bsum, boff, nb);
    scan_add_kernel<<<nb, 256, 0, stream>>>(rowptr, boff, deg, invd, N, E);
    fill_kernel<<<(E + 255) / 256, 256, 0, stream>>>(esrc, edst, rowptr, fillc, srcs, E);

    const u16* cur = xb;
    const unsigned char* curq = (const unsigned char*)xq;
    for (int s = 0; s <= L; ++s) {
        int fin = (s == L) ? 1 : 0;
        agg_kernel<<<NPAD / 4, 256, 0, stream>>>(curq, mb, rowptr, srcs, invd, N, NPAD);
        // in-place h update is safe: each gemm block reads exactly the rows it writes,
        // and all its reads (K-loop) precede its writes (epilogue).
        gemm_kernel<<<NPAD / 128, 256, 0, stream>>>(mb, cur, wT + (size_t)s * 512 * 256, hbuf,
                                                    Wo, bo, out, N, s > 0 ? 1 : 0, fin);
        if (!fin) {
            cvt_h_kernel<<<(N * 32 + 255) / 256, 256, 0, stream>>>(hbuf, hq, N * 32);
            cur = hbuf;
            curq = (const unsigned char*)hq;
        }
    }
}

// Round 4
// 341.785 us; speedup vs baseline: 1.4873x; 1.1481x over previous
//
#include <hip/hip_runtime.h>

typedef unsigned short u16;
typedef unsigned int u32;
typedef __attribute__((ext_vector_type(8))) short short8;
typedef __attribute__((ext_vector_type(4))) float f32x4;
typedef __attribute__((ext_vector_type(2))) float f32x2;

__device__ __forceinline__ float bf2f(u16 u) {
    return __uint_as_float(((u32)u) << 16);
}
__device__ __forceinline__ u16 f2bf(float f) {
    u32 u = __float_as_uint(f);
    u += 0x7fff + ((u >> 16) & 1);   // round-to-nearest-even
    return (u16)(u >> 16);
}
__device__ __forceinline__ u32 pack2(float a, float b) {
    return (u32)f2bf(a) | ((u32)f2bf(b) << 16);
}
// pack 4 floats -> 4 fp8 e4m3 in one u32
__device__ __forceinline__ u32 pk_fp8x4(float f0, float f1, float f2, float f3) {
    int w = __builtin_amdgcn_cvt_pk_fp8_f32(f0, f1, 0, false);
    w = __builtin_amdgcn_cvt_pk_fp8_f32(f2, f3, w, true);
    return (u32)w;
}
// accumulate 4 fp8 (one u32) into a[0..3]
__device__ __forceinline__ void acc4(float* a, u32 w) {
    f32x2 lo = __builtin_amdgcn_cvt_pk_f32_fp8((int)w, false);
    f32x2 hi = __builtin_amdgcn_cvt_pk_f32_fp8((int)w, true);
    a[0] += lo.x; a[1] += lo.y; a[2] += hi.x; a[3] += hi.y;
}
__device__ __forceinline__ void acc4m(float* a, u32 w, float m) {
    f32x2 lo = __builtin_amdgcn_cvt_pk_f32_fp8((int)w, false);
    f32x2 hi = __builtin_amdgcn_cvt_pk_f32_fp8((int)w, true);
    a[0] += m * lo.x; a[1] += m * lo.y; a[2] += m * hi.x; a[3] += m * hi.y;
}
__device__ __forceinline__ void acc16(float* a, uint4 v) {
    acc4(a + 0, v.x); acc4(a + 4, v.y); acc4(a + 8, v.z); acc4(a + 12, v.w);
}
__device__ __forceinline__ void acc16m(float* a, uint4 v, float m) {
    acc4m(a + 0, v.x, m); acc4m(a + 4, v.y, m); acc4m(a + 8, v.z, m); acc4m(a + 12, v.w, m);
}

// ---------------- conversions ----------------

// x fp32 -> xb bf16 [NPAD][256]  and  xq fp8 [NPAD][256]
__global__ void cvt_x_kernel(const float* __restrict__ x, u16* __restrict__ xb,
                             u32* __restrict__ xq, int n) {
    int i = blockIdx.x * 256 + threadIdx.x;   // group of 4 elements
    int row = i >> 6;                         // 64 groups per 256-wide row
    ushort4 o;
    u32 q;
    if (row < n) {
        float4 v = ((const float4*)x)[i];
        o.x = f2bf(v.x); o.y = f2bf(v.y); o.z = f2bf(v.z); o.w = f2bf(v.w);
        q = pk_fp8x4(v.x, v.y, v.z, v.w);
    } else {
        o.x = o.y = o.z = o.w = 0;
        q = 0;
    }
    ((ushort4*)xb)[i] = o;
    xq[i] = q;
}

// h bf16 -> fp8 copy (8 feats per thread)
__global__ void cvt_h_kernel(const u16* __restrict__ hb, uint2* __restrict__ hq, int ngroups) {
    int j = blockIdx.x * 256 + threadIdx.x;
    if (j >= ngroups) return;
    uint4 v = ((const uint4*)hb)[j];
    float f0 = bf2f(v.x & 0xffff), f1 = bf2f(v.x >> 16);
    float f2 = bf2f(v.y & 0xffff), f3 = bf2f(v.y >> 16);
    float f4 = bf2f(v.z & 0xffff), f5 = bf2f(v.z >> 16);
    float f6 = bf2f(v.w & 0xffff), f7 = bf2f(v.w >> 16);
    uint2 o;
    o.x = pk_fp8x4(f0, f1, f2, f3);
    o.y = pk_fp8x4(f4, f5, f6, f7);
    hq[j] = o;
}

// wT layout: [layer][n=256][k=512], k-contiguous (transposed weights, A rows then B rows)
__global__ void cvt_w_kernel(const float* __restrict__ WA, const float* __restrict__ WB,
                             const float* __restrict__ As, const float* __restrict__ Bs,
                             u16* __restrict__ wT, int nlayers) {
    int i = blockIdx.x * 256 + threadIdx.x;
    const int per = 256 * 512;
    if (i >= nlayers * per) return;
    int l = i / per;
    int rem = i - l * per;
    int nn = rem >> 9;
    int k = rem & 511;
    const float* Aw = (l == 0) ? WA : As + (size_t)(l - 1) * 65536;
    const float* Bw = (l == 0) ? WB : Bs + (size_t)(l - 1) * 65536;
    float v = (k < 256) ? Aw[(size_t)k * 256 + nn] : Bw[(size_t)(k - 256) * 256 + nn];
    wT[i] = f2bf(v);
}

// ---------------- CSR build: two-level counting sort ----------------
// Requires N <= 65536 so an edge packs into u32 as (dst<<16)|src.
// Coarse bucket b covers nodes [b*256, b*256+256).

// per-block LDS histogram of coarse buckets -> global ccnt[NB]
__global__ __launch_bounds__(256) void hist_kernel(const int* __restrict__ dst,
                                                   int* __restrict__ ccnt, int e, int nb) {
    __shared__ int h[256];
    int tid = threadIdx.x;
    h[tid] = 0;
    __syncthreads();
    int e0 = blockIdx.x * 4096;
#pragma unroll
    for (int j = 0; j < 16; ++j) {
        int i = e0 + j * 256 + tid;
        if (i < e) atomicAdd(&h[dst[i] >> 8], 1);
    }
    __syncthreads();
    if (tid < nb) {
        int v = h[tid];
        if (v) atomicAdd(&ccnt[tid], v);
    }
}

// single-block scan of coarse counts -> cbase[NB+1]; also rowptr[n]=e
__global__ __launch_bounds__(256) void scan_coarse_kernel(const int* __restrict__ ccnt,
                                                          int* __restrict__ cbase,
                                                          int* __restrict__ rowptr,
                                                          int nb, int n, int e) {
    __shared__ int sh[256];
    int t = threadIdx.x;
    int v = (t < nb) ? ccnt[t] : 0;
    int x = v;
    sh[t] = x; __syncthreads();
    for (int o = 1; o < 256; o <<= 1) {
        int y = (t >= o) ? sh[t - o] : 0;
        __syncthreads();
        x += y; sh[t] = x; __syncthreads();
    }
    if (t < nb) cbase[t] = x - v;
    if (t == 0) { cbase[nb] = e; rowptr[n] = e; }
}

// scatter packed edges into coarse regions of tmp; per-block chunk reservation
__global__ __launch_bounds__(256) void passA_kernel(const int* __restrict__ src,
                                                    const int* __restrict__ dst,
                                                    const int* __restrict__ cbase,
                                                    int* __restrict__ cfill,
                                                    u32* __restrict__ tmp, int e, int nb) {
    __shared__ int ph[256], pb[256], pr[256], cb[256];
    __shared__ u32 ed[4096];
    int tid = threadIdx.x;
    ph[tid] = 0; pr[tid] = 0;
    cb[tid] = (tid < nb) ? cbase[tid] : 0;
    __syncthreads();
    int e0 = blockIdx.x * 4096;
#pragma unroll
    for (int j = 0; j < 16; ++j) {
        int i = e0 + j * 256 + tid;
        u32 p = 0xFFFFFFFFu;
        if (i < e) {
            int d = dst[i];
            p = ((u32)d << 16) | (u32)src[i];
            atomicAdd(&ph[d >> 8], 1);
        }
        ed[j * 256 + tid] = p;
    }
    __syncthreads();
    pb[tid] = (tid < nb && ph[tid]) ? atomicAdd(&cfill[tid], ph[tid]) : 0;
    __syncthreads();
#pragma unroll
    for (int j = 0; j < 16; ++j) {
        u32 p = ed[j * 256 + tid];
        if (p != 0xFFFFFFFFu) {
            int bk = p >> 24;
            int r = atomicAdd(&pr[bk], 1);
            tmp[cb[bk] + pb[bk] + r] = p;
        }
    }
}

// per coarse bucket: per-node hist + scan -> rowptr/invd, then LDS-ranked scatter -> srcs
__global__ __launch_bounds__(256) void passB_kernel(const u32* __restrict__ tmp,
                                                    const int* __restrict__ cbase,
                                                    int* __restrict__ rowptr,
                                                    float* __restrict__ invd,
                                                    int* __restrict__ srcs, int n) {
    __shared__ int h[256], loc[256], cnt2[256], sh[256];
    int b = blockIdx.x;
    int tid = threadIdx.x;
    int base = cbase[b];
    int cnt = cbase[b + 1] - base;
    int node0 = b << 8;
    h[tid] = 0; cnt2[tid] = 0;
    __syncthreads();
    for (int i = tid; i < cnt; i += 256)
        atomicAdd(&h[(tmp[base + i] >> 16) & 255], 1);
    __syncthreads();
    int c = h[tid];
    int x = c;
    sh[tid] = x; __syncthreads();
    for (int o = 1; o < 256; o <<= 1) {
        int y = (tid >= o) ? sh[tid - o] : 0;
        __syncthreads();
        x += y; sh[tid] = x; __syncthreads();
    }
    loc[tid] = x - c;   // exclusive offset within bucket
    int node = node0 + tid;
    if (node < n) {
        rowptr[node] = base + x - c;
        invd[node] = 1.0f / (float)(c > 0 ? c : 1);
    }
    __syncthreads();
    for (int i = tid; i < cnt; i += 256) {
        u32 p = tmp[base + i];
        int ln = (p >> 16) & 255;
        int r = atomicAdd(&cnt2[ln], 1);
        srcs[base + loc[ln] + r] = (int)(p & 0xffffu);
    }
}

// ---------------- mean aggregation: one wave per node, fp8 gather ----------------
// fp8 row = 256B; 16 lanes x 16B cover a row; 4 edges per wave-load, x2 unroll
// -> 8 edges in flight. Output mean row written as bf16 to mb.

__global__ __launch_bounds__(256) void agg_kernel(const unsigned char* __restrict__ q,
                                                  u16* __restrict__ mb,
                                                  const int* __restrict__ rowptr,
                                                  const int* __restrict__ srcs,
                                                  const float* __restrict__ invd,
                                                  int n, int npad) {
    int gw = (blockIdx.x * 256 + threadIdx.x) >> 6;  // node id
    int lane = threadIdx.x & 63;
    int qd = lane >> 4;          // edge slot within group of 4
    int fl = lane & 15;          // 16B chunk (16 feats) within the row
    if (gw >= npad) return;
    u16* orow = mb + (size_t)gw * 256;
    if (gw >= n) {
        if (lane < 16) {
            uint4 z; z.x = z.y = z.z = z.w = 0;
            uint4* p = (uint4*)(orow + lane * 16);
            p[0] = z; p[1] = z;
        }
        return;
    }
    int beg = rowptr[gw], end = rowptr[gw + 1];
    float a[16];
#pragma unroll
    for (int i = 0; i < 16; ++i) a[i] = 0.f;
    for (int base = beg; base < end; base += 64) {
        int cnt = end - base;
        if (cnt > 64) cnt = 64;
        int el = (lane < cnt) ? srcs[base + lane] : 0;
        int t = 0;
        for (; 4 * t + 8 <= cnt; t += 2) {
            int s0 = __shfl(el, 4 * t + qd);
            int s1 = __shfl(el, 4 * t + 4 + qd);
            uint4 v0 = *(const uint4*)(q + (size_t)s0 * 256 + fl * 16);
            uint4 v1 = *(const uint4*)(q + (size_t)s1 * 256 + fl * 16);
            acc16(a, v0);
            acc16(a, v1);
        }
        for (; 4 * t < cnt; ++t) {
            int ei = 4 * t + qd;
            int sj = __shfl(el, ei & 63);
            float m = (ei < cnt) ? 1.0f : 0.0f;
            uint4 v = *(const uint4*)(q + (size_t)sj * 256 + fl * 16);
            acc16m(a, v, m);
        }
    }
    // reduce the 4 quarters
#pragma unroll
    for (int i = 0; i < 16; ++i) {
        a[i] += __shfl_xor(a[i], 16);
        a[i] += __shfl_xor(a[i], 32);
    }
    if (lane < 16) {
        float sc = invd[gw];
        uint4 o0, o1;
        o0.x = pack2(a[0] * sc, a[1] * sc);
        o0.y = pack2(a[2] * sc, a[3] * sc);
        o0.z = pack2(a[4] * sc, a[5] * sc);
        o0.w = pack2(a[6] * sc, a[7] * sc);
        o1.x = pack2(a[8] * sc, a[9] * sc);
        o1.y = pack2(a[10] * sc, a[11] * sc);
        o1.z = pack2(a[12] * sc, a[13] * sc);
        o1.w = pack2(a[14] * sc, a[15] * sc);
        uint4* p = (uint4*)(orow + lane * 16);
        p[0] = o0; p[1] = o1;
    }
}

// ---------------- fused GEMM: out = act([m | cur] @ wT^T), 128x256 tile ----------------
// A: rows from m (k<256) then cur (k>=256), both [NPAD][256] bf16 row-major.
// B: wT layer slice [n=256][k=512] bf16, k-contiguous. One block covers all 256 cols.
// fin=1: instead of storing h, dot rows against wo (fp32 [256]) + bias -> out[row].

__global__ __launch_bounds__(256, 2) void gemm_kernel(const u16* __restrict__ mA,
                                                      const u16* __restrict__ cur,
                                                      const u16* __restrict__ wT,
                                                      u16* __restrict__ outb,
                                                      const float* __restrict__ wo,
                                                      const float* __restrict__ bo,
                                                      float* __restrict__ out,
                                                      int n, int apply_sigmoid, int fin) {
    __shared__ u16 lA[128 * 32];
    __shared__ u16 lB[256 * 32];
    __shared__ float lO[2][128];
    int r0 = blockIdx.x * 128;
    int tid = threadIdx.x;
    int lane = tid & 63;
    int w = tid >> 6;
    int wrow = w >> 1, wcol = w & 1;   // wave: rows wrow*64.., cols wcol*128..
    int lrow = lane & 15, quad = lane >> 4;

    f32x4 acc[4][8] = {};

    for (int ks = 0; ks < 16; ++ks) {
        int k0 = ks * 32;
        const u16* srcA = (k0 < 256) ? mA : cur;
        int kk = k0 & 255;
        __syncthreads();
#pragma unroll
        for (int p = 0; p < 2; ++p) {
            int li = p * 256 + tid;        // 0..511
            int row = li >> 2;             // 0..127
            int seg = (li & 3) << 3;       // elem offset 0,8,16,24
            const u16* gA = srcA + (size_t)(r0 + row) * 256 + kk + seg;
            __builtin_amdgcn_global_load_lds(
                (__attribute__((address_space(1))) u32*)(gA),
                (__attribute__((address_space(3))) u32*)(lA + (size_t)li * 8), 16, 0, 0);
        }
#pragma unroll
        for (int p = 0; p < 4; ++p) {
            int li = p * 256 + tid;        // 0..1023
            int row = li >> 2;             // 0..255
            int seg = (li & 3) << 3;
            const u16* gB = wT + (size_t)row * 512 + k0 + seg;
            __builtin_amdgcn_global_load_lds(
                (__attribute__((address_space(1))) u32*)(gB),
                (__attribute__((address_space(3))) u32*)(lB + (size_t)li * 8), 16, 0, 0);
        }
        __syncthreads();

        short8 a[4], b[8];
#pragma unroll
        for (int t = 0; t < 4; ++t)
            a[t] = *(const short8*)(lA + ((size_t)(wrow * 64 + t * 16 + lrow) * 32 + quad * 8));
#pragma unroll
        for (int t = 0; t < 8; ++t)
            b[t] = *(const short8*)(lB + ((size_t)(wcol * 128 + t * 16 + lrow) * 32 + quad * 8));
#pragma unroll
        for (int rt = 0; rt < 4; ++rt)
#pragma unroll
            for (int ct = 0; ct < 8; ++ct)
                acc[rt][ct] = __builtin_amdgcn_mfma_f32_16x16x32_bf16(a[rt], b[ct], acc[rt][ct], 0, 0, 0);
    }

    if (!fin) {
#pragma unroll
        for (int rt = 0; rt < 4; ++rt) {
            int rbase = r0 + wrow * 64 + rt * 16 + quad * 4;
#pragma unroll
            for (int r = 0; r < 4; ++r) {
                int row = rbase + r;
                if (row < n) {
#pragma unroll
                    for (int ct = 0; ct < 8; ++ct) {
                        float v = acc[rt][ct][r];
                        if (apply_sigmoid) v = 1.0f / (1.0f + __expf(-v));
                        outb[(size_t)row * 256 + wcol * 128 + ct * 16 + lrow] = f2bf(v);
                    }
                }
            }
        }
    } else {
        // final layer: sigmoid then dot with wo, reduce, write out
        float wv[8];
#pragma unroll
        for (int ct = 0; ct < 8; ++ct) wv[ct] = wo[wcol * 128 + ct * 16 + lrow];
#pragma unroll
        for (int rt = 0; rt < 4; ++rt) {
#pragma unroll
            for (int r = 0; r < 4; ++r) {
                float s = 0.f;
#pragma unroll
                for (int ct = 0; ct < 8; ++ct) {
                    float v = acc[rt][ct][r];
                    v = 1.0f / (1.0f + __expf(-v));
                    s += v * wv[ct];
                }
                // reduce across the 16 lanes (lrow bits 0..3) sharing this row
                s += __shfl_xor(s, 1);
                s += __shfl_xor(s, 2);
                s += __shfl_xor(s, 4);
                s += __shfl_xor(s, 8);
                if (lrow == 0) {
                    int rowlocal = wrow * 64 + rt * 16 + quad * 4 + r;
                    lO[wcol][rowlocal] = s;
                }
            }
        }
        __syncthreads();
        if (tid < 128) {
            int row = r0 + tid;
            if (row < n) out[row] = lO[0][tid] + lO[1][tid] + bo[0];
        }
    }
}

// ---------------- launch ----------------

extern "C" void kernel_launch(void* const* d_in, const int* in_sizes, int n_in,
                              void* d_out, int out_size, void* d_ws, size_t ws_size,
                              hipStream_t stream) {
    const float* x  = (const float*)d_in[0];
    const int*   ei = (const int*)d_in[1];
    const float* WA = (const float*)d_in[2];
    const float* WB = (const float*)d_in[3];
    const float* As = (const float*)d_in[4];
    const float* Bs = (const float*)d_in[5];
    const float* Wo = (const float*)d_in[6];
    const float* bo = (const float*)d_in[7];
    float* out = (float*)d_out;

    const int H = 256;
    int N = in_sizes[0] / H;
    int E = in_sizes[1] / 2;
    int L = in_sizes[4] / (H * H);
    int NPAD = (N + 127) & ~127;
    int NB = (N + 255) >> 8;           // coarse buckets (requires N <= 65536)

    char* wsp = (char*)d_ws;
    size_t off = 0;
    auto alloc = [&](size_t b) { size_t o = off; off += (b + 255) & ~(size_t)255; return o; };
    int*   rowptr = (int*)(wsp + alloc((size_t)(NPAD + 1) * 4));
    int*   ccnt   = (int*)(wsp + alloc(1024));
    int*   cbase  = (int*)(wsp + alloc(1032 + 256));
    int*   cfill  = (int*)(wsp + alloc(1024));
    float* invd   = (float*)(wsp + alloc((size_t)NPAD * 4));
    int*   srcs   = (int*)(wsp + alloc((size_t)E * 4));
    u16*   xb     = (u16*)(wsp + alloc((size_t)NPAD * H * 2));
    u16*   hbuf   = (u16*)(wsp + alloc((size_t)NPAD * H * 2));
    u16*   mb     = (u16*)(wsp + alloc((size_t)NPAD * H * 2));
    u32*   xq     = (u32*)(wsp + alloc((size_t)NPAD * H));      // fp8 x
    uint2* hq     = (uint2*)(wsp + alloc((size_t)NPAD * H));    // fp8 h
    u16*   wT     = (u16*)(wsp + alloc((size_t)(L + 1) * 512 * 256 * 2));
    // tmp (packed coarse-sorted edges) aliases mb: dead until first agg writes mb
    u32*   tmp    = (u32*)mb;

    const int* esrc = ei;
    const int* edst = ei + E;

    hipMemsetAsync(ccnt, 0, 1024, stream);
    hipMemsetAsync(cfill, 0, 1024, stream);

    int gridE = (E + 4095) / 4096;
    cvt_x_kernel<<<NPAD / 4, 256, 0, stream>>>(x, xb, xq, N);
    cvt_w_kernel<<<((L + 1) * 512 * 256 + 255) / 256, 256, 0, stream>>>(WA, WB, As, Bs, wT, L + 1);
    hist_kernel<<<gridE, 256, 0, stream>>>(edst, ccnt, E, NB);
    scan_coarse_kernel<<<1, 256, 0, stream>>>(ccnt, cbase, rowptr, NB, N, E);
    passA_kernel<<<gridE, 256, 0, stream>>>(esrc, edst, cbase, cfill, tmp, E, NB);
    passB_kernel<<<NB, 256, 0, stream>>>(tmp, cbase, rowptr, invd, srcs, N);

    const u16* cur = xb;
    const unsigned char* curq = (const unsigned char*)xq;
    for (int s = 0; s <= L; ++s) {
        int fin = (s == L) ? 1 : 0;
        agg_kernel<<<NPAD / 4, 256, 0, stream>>>(curq, mb, rowptr, srcs, invd, N, NPAD);
        gemm_kernel<<<NPAD / 128, 256, 0, stream>>>(mb, cur, wT + (size_t)s * 512 * 256, hbuf,
                                                    Wo, bo, out, N, s > 0 ? 1 : 0, fin);
        if (!fin) {
            cvt_h_kernel<<<(N * 32 + 255) / 256, 256, 0, stream>>>(hbuf, hq, N * 32);
            cur = hbuf;
            curq = (const unsigned char*)hq;
        }
    }
}